// Round 1
// baseline (1256.912 us; speedup 1.0000x reference)
//
#include <hip/hip_runtime.h>
#include <math.h>

#define NODES_HIDDEN 128
#define N_HEADS 8
#define HEAD_DIM 16

// ---------------- generic linear: out[N,O] = act(in[N,K] @ W[O,K]^T + b) ----
// BN=32 nodes per block, BO=64 outputs per blockIdx.y, BK=128 k-chunk.
constexpr int BN = 32, BO = 64, BK = 128, BKP = BK + 4;

__global__ __launch_bounds__(256)
void linear_kernel(const float* __restrict__ in, const float* __restrict__ W,
                   const float* __restrict__ bias, float* __restrict__ out,
                   int N, int K, int O, int act)
{
    __shared__ float Ws[BO][BKP];
    __shared__ float xs[BN][BKP];
    const int tid = threadIdx.x;
    const int ty = tid >> 3;   // 0..31 node within tile
    const int tx = tid & 7;    // 0..7
    const int n0 = blockIdx.x * BN;
    const int o0 = blockIdx.y * BO;

    float acc[8];
#pragma unroll
    for (int j = 0; j < 8; ++j) acc[j] = 0.f;

    for (int kc = 0; kc < K; kc += BK) {
        // load W tile: BO x BK floats as float4 (2048 float4 / 256 thr = 8 ea)
#pragma unroll
        for (int i = 0; i < 8; ++i) {
            int idx = i * 256 + tid;
            int row = idx >> 5;
            int c4  = idx & 31;
            float4 wv = *(const float4*)&W[(size_t)(o0 + row) * K + kc + c4 * 4];
            *(float4*)&Ws[row][c4 * 4] = wv;
        }
        // load x tile: BN x BK floats (1024 float4 / 256 thr = 4 ea)
#pragma unroll
        for (int i = 0; i < 4; ++i) {
            int idx = i * 256 + tid;
            int row = idx >> 5;
            int c4  = idx & 31;
            float4 xv = make_float4(0.f, 0.f, 0.f, 0.f);
            if (n0 + row < N)
                xv = *(const float4*)&in[(size_t)(n0 + row) * K + kc + c4 * 4];
            *(float4*)&xs[row][c4 * 4] = xv;
        }
        __syncthreads();
#pragma unroll 8
        for (int k = 0; k < BK; k += 4) {
            float4 xv = *(const float4*)&xs[ty][k];
#pragma unroll
            for (int j = 0; j < 8; ++j) {
                float4 wv = *(const float4*)&Ws[tx + j * 8][k];
                acc[j] += xv.x * wv.x + xv.y * wv.y + xv.z * wv.z + xv.w * wv.w;
            }
        }
        __syncthreads();
    }

    const int n = n0 + ty;
    if (n < N) {
#pragma unroll
        for (int j = 0; j < 8; ++j) {
            int o = o0 + tx + j * 8;
            float v = acc[j] + bias[o];
            if (act == 1) v = 0.5f * v * (1.f + erff(v * 0.70710678118654752f));
            out[(size_t)n * O + o] = v;
        }
    }
}

// ---------------- edge pass A: alpha + segment-max (encoded-uint atomicMax) --
__device__ __forceinline__ unsigned int enc_f(float f) {
    unsigned int u = __float_as_uint(f);
    return (u & 0x80000000u) ? ~u : (u | 0x80000000u);
}
__device__ __forceinline__ float dec_f(unsigned int u) {
    return __uint_as_float((u & 0x80000000u) ? (u & 0x7FFFFFFFu) : ~u);
}

__global__ __launch_bounds__(256)
void edge_scores_kernel(const float* __restrict__ q, const float* __restrict__ k,
                        const int* __restrict__ src, const int* __restrict__ dst,
                        float* __restrict__ alpha, unsigned int* __restrict__ m,
                        int E)
{
    int idx = blockIdx.x * 256 + threadIdx.x;
    if (idx >= E * N_HEADS) return;
    int e = idx >> 3, hd = idx & 7;
    int s = src[e], d = dst[e];
    const float4* qp = (const float4*)&q[(size_t)d * NODES_HIDDEN + hd * HEAD_DIM];
    const float4* kp = (const float4*)&k[(size_t)s * NODES_HIDDEN + hd * HEAD_DIM];
    float dotv = 0.f;
#pragma unroll
    for (int i = 0; i < 4; ++i) {
        float4 qv = qp[i], kv = kp[i];
        dotv += qv.x * kv.x + qv.y * kv.y + qv.z * kv.z + qv.w * kv.w;
    }
    float a = dotv * 0.25f;   // 1/sqrt(16)
    alpha[idx] = a;
    atomicMax(&m[d * N_HEADS + hd], enc_f(a));
}

// ---------------- edge pass B: ea = exp(a-m); agg += ea*v; denom += ea -------
__global__ __launch_bounds__(256)
void edge_agg_kernel(const float* __restrict__ v, const int* __restrict__ src,
                     const int* __restrict__ dst, const float* __restrict__ alpha,
                     const unsigned int* __restrict__ m, float* __restrict__ agg,
                     float* __restrict__ denom, int E)
{
    int idx = blockIdx.x * 256 + threadIdx.x;
    if (idx >= E * NODES_HIDDEN) return;   // 102.4M < 2^31
    int e = idx >> 7, c = idx & 127, hd = c >> 4;
    int s = src[e], d = dst[e];
    float a  = alpha[e * N_HEADS + hd];
    float mv = dec_f(m[d * N_HEADS + hd]);
    float ea = __expf(a - mv);
    if ((c & 15) == 0) atomicAdd(&denom[d * N_HEADS + hd], ea);
    atomicAdd(&agg[(size_t)d * NODES_HIDDEN + c], ea * v[(size_t)s * NODES_HIDDEN + c]);
}

// ---------------- normalize agg by denom ------------------------------------
__global__ __launch_bounds__(256)
void norm_agg_kernel(float* __restrict__ agg, const float* __restrict__ denom, int N)
{
    int idx = blockIdx.x * 256 + threadIdx.x;
    if (idx >= N * NODES_HIDDEN) return;
    int n = idx >> 7, hd = (idx & 127) >> 4;
    agg[idx] = agg[idx] / (denom[n * N_HEADS + hd] + 1e-16f);
}

// ---------------- fused add + layernorm: out = LN(a+b)*g+be ------------------
__global__ __launch_bounds__(256)
void add_ln_kernel(const float* __restrict__ a, const float* __restrict__ b,
                   const float* __restrict__ g, const float* __restrict__ be,
                   float* __restrict__ out, int N)
{
    int wave = threadIdx.x >> 6;
    int lane = threadIdx.x & 63;
    int n = blockIdx.x * 4 + wave;
    if (n >= N) return;
    int c = lane * 2;
    float2 av = *(const float2*)&a[(size_t)n * NODES_HIDDEN + c];
    float2 bv = *(const float2*)&b[(size_t)n * NODES_HIDDEN + c];
    float v0 = av.x + bv.x, v1 = av.y + bv.y;
    float s = v0 + v1;
#pragma unroll
    for (int off = 32; off; off >>= 1) s += __shfl_down(s, off);
    s = __shfl(s, 0);
    float mu = s * (1.f / 128.f);
    float d0 = v0 - mu, d1 = v1 - mu;
    float vs = d0 * d0 + d1 * d1;
#pragma unroll
    for (int off = 32; off; off >>= 1) vs += __shfl_down(vs, off);
    vs = __shfl(vs, 0);
    float rstd = rsqrtf(vs * (1.f / 128.f) + 1e-5f);
    out[(size_t)n * NODES_HIDDEN + c]     = d0 * rstd * g[c] + be[c];
    out[(size_t)n * NODES_HIDDEN + c + 1] = d1 * rstd * g[c + 1] + be[c + 1];
}

// ============================================================================
extern "C" void kernel_launch(void* const* d_in, const int* in_sizes, int n_in,
                              void* d_out, int out_size, void* d_ws, size_t ws_size,
                              hipStream_t stream)
{
    const float* x  = (const float*)d_in[0];
    const int*   ei = (const int*)d_in[1];
    const float* Wq = (const float*)d_in[2];
    const float* bq = (const float*)d_in[3];
    const float* Wk = (const float*)d_in[4];
    const float* bk = (const float*)d_in[5];
    const float* Wv = (const float*)d_in[6];
    const float* bv = (const float*)d_in[7];
    const float* Wo = (const float*)d_in[8];
    const float* bo = (const float*)d_in[9];
    const float* W1 = (const float*)d_in[10];
    const float* b1 = (const float*)d_in[11];
    const float* W2 = (const float*)d_in[12];
    const float* b2 = (const float*)d_in[13];
    const float* g1 = (const float*)d_in[14];
    const float* be1= (const float*)d_in[15];
    const float* g2 = (const float*)d_in[16];
    const float* be2= (const float*)d_in[17];
    float* out = (float*)d_out;

    const int N = in_sizes[0] / NODES_HIDDEN;       // 50000
    const int E = in_sizes[1] / 2;                  // 800000
    const int* srcp = ei;           // edge_index[0] = source (k/v side)
    const int* dstp = ei + E;       // edge_index[1] = destination (q side)

    const size_t NH = (size_t)N * NODES_HIDDEN;     // 6.4M floats
    const size_t N8 = (size_t)N * N_HEADS;          // 0.4M floats
    float* wsf   = (float*)d_ws;
    float* q     = wsf;                  // NH   [later: att, then ff2 out]
    float* kbuf  = wsf + NH;             // NH   [later: ffh spans kbuf..kbuf+4NH]
    float* vbuf  = wsf + 2 * NH;         // NH
    float* alpha = wsf + 3 * NH;         // E*8 == NH floats exactly
    float* agg   = wsf + 4 * NH;         // NH
    float* mbuf  = wsf + 5 * NH;         // N8 (uint-encoded)
    float* denom = wsf + 5 * NH + N8;    // N8
    float* h     = wsf + 5 * NH + 2 * N8;// NH
    float* ffh   = kbuf;                 // N*512 = 4*NH floats (overlays k,v,alpha,agg)
    float* att   = q;                    // reuse
    float* ff2   = q;                    // reuse

    const int gx = (N + BN - 1) / BN;    // 1563

    // QKV projections
    linear_kernel<<<dim3(gx, 2), 256, 0, stream>>>(x, Wq, bq, q,    N, 128, 128, 0);
    linear_kernel<<<dim3(gx, 2), 256, 0, stream>>>(x, Wk, bk, kbuf, N, 128, 128, 0);
    linear_kernel<<<dim3(gx, 2), 256, 0, stream>>>(x, Wv, bv, vbuf, N, 128, 128, 0);

    // zero agg + m + denom (contiguous region). enc(-inf)=0x007FFFFF > 0, so 0 is
    // a valid atomicMax identity for the encoded max buffer.
    hipMemsetAsync(agg, 0, (NH + 2 * N8) * sizeof(float), stream);

    // edge pass A: scores + segment max
    {
        int total = E * N_HEADS;
        edge_scores_kernel<<<(total + 255) / 256, 256, 0, stream>>>(
            q, kbuf, srcp, dstp, alpha, (unsigned int*)mbuf, E);
    }
    // edge pass B: exp + scatter-add (unnormalized)
    {
        long long total = (long long)E * NODES_HIDDEN;
        edge_agg_kernel<<<(int)((total + 255) / 256), 256, 0, stream>>>(
            vbuf, srcp, dstp, alpha, (const unsigned int*)mbuf, agg, denom, E);
    }
    // normalize
    norm_agg_kernel<<<(int)((NH + 255) / 256), 256, 0, stream>>>(agg, denom, N);

    // output projection + residual + LN1
    linear_kernel<<<dim3(gx, 2), 256, 0, stream>>>(agg, Wo, bo, att, N, 128, 128, 0);
    add_ln_kernel<<<(N + 3) / 4, 256, 0, stream>>>(x, att, g1, be1, h, N);

    // FFN
    linear_kernel<<<dim3(gx, 8), 256, 0, stream>>>(h,   W1, b1, ffh, N, 128, 512, 1);
    linear_kernel<<<dim3(gx, 2), 256, 0, stream>>>(ffh, W2, b2, ff2, N, 512, 128, 0);
    add_ln_kernel<<<(N + 3) / 4, 256, 0, stream>>>(h, ff2, g2, be2, out, N);
}

// Round 2
// 858.795 us; speedup vs baseline: 1.4636x; 1.4636x over previous
//
#include <hip/hip_runtime.h>
#include <math.h>

#define N_HEADS 8
#define HEAD_DIM 16
#define HID 128
#define QKV_STRIDE 384

typedef unsigned short ushort_t;
typedef __attribute__((ext_vector_type(8))) short short8;
typedef __attribute__((ext_vector_type(4))) float floatx4;

__device__ __forceinline__ ushort_t f2bf(float f) {
    unsigned u = __float_as_uint(f);
    unsigned r = (u + 0x7FFFu + ((u >> 16) & 1u)) >> 16;
    return (ushort_t)r;
}

__device__ __forceinline__ void gld_lds16(const void* g, void* l) {
    __builtin_amdgcn_global_load_lds(
        (const __attribute__((address_space(1))) void*)g,
        (__attribute__((address_space(3))) void*)l, 16, 0, 0);
}

// ---------------- f32 -> bf16 conversion (2 elems/thread) --------------------
__global__ __launch_bounds__(256)
void cvt_bf16_kernel(const float* __restrict__ in, ushort_t* __restrict__ out, int n2)
{
    int i = blockIdx.x * 256 + threadIdx.x;
    if (i >= n2) return;
    float2 v = *(const float2*)&in[i * 2];
    out[i * 2]     = f2bf(v.x);
    out[i * 2 + 1] = f2bf(v.y);
}

// ---------------- bf16 MFMA GEMM: out[M,O] = act(A[M,K] @ W[O,K]^T + b) ------
// Block: 256 thr = 4 waves (2x2 over 128x128 tile). BK=64 chunks.
// LDS fragment-major: slot s=(tile*2+kstep)*64+lane holds 16B =
//   X[tile*16 + (lane&15)][kstep*32 + (lane>>4)*8 .. +8) — conflict-free ds_read_b128,
//   and lane-contiguous so global_load_lds (wave base + lane*16) lands correctly.
__global__ __launch_bounds__(256)
void gemm_bf16(const ushort_t* __restrict__ A, int lda, int M,
               const ushort_t* __restrict__ W, int K,
               const float* __restrict__ bias,
               float* __restrict__ outf, ushort_t* __restrict__ outb,
               int ostride, int act)
{
    __shared__ __align__(16) ushort_t As[128 * 64];
    __shared__ __align__(16) ushort_t Ws[128 * 64];
    const int tid  = threadIdx.x;
    const int wave = tid >> 6, lane = tid & 63;
    const int gm0 = blockIdx.x * 128;
    const int o0  = blockIdx.y * 128;
    const int mhalf = wave >> 1, ohalf = wave & 1;

    floatx4 acc[4][4];
#pragma unroll
    for (int i = 0; i < 4; ++i)
#pragma unroll
        for (int j = 0; j < 4; ++j) acc[i][j] = (floatx4)(0.f);

    for (int kc = 0; kc < K; kc += 64) {
#pragma unroll
        for (int it = 0; it < 4; ++it) {
            int s   = it * 256 + tid;
            int ln  = s & 63;
            int grp = s >> 6;               // 0..15
            int tile = grp >> 1, kst = grp & 1;
            int row = tile * 16 + (ln & 15);
            int kk  = kst * 32 + (ln >> 4) * 8;
            int ldsbase = (it * 256 + wave * 64) * 8;   // ushort elems (16B slots)
            // A tile (clamp tail rows; garbage only lands in rows >= M)
            int ar = gm0 + row; if (ar >= M) ar = M - 1;
            gld_lds16(&A[(size_t)ar * lda + kc + kk], &As[ldsbase]);
            // W tile
            gld_lds16(&W[(size_t)(o0 + row) * K + kc + kk], &Ws[ldsbase]);
        }
        __syncthreads();
#pragma unroll
        for (int kst = 0; kst < 2; ++kst) {
            short8 af[4], wf[4];
#pragma unroll
            for (int i = 0; i < 4; ++i) {
                int mt = mhalf * 4 + i;
                af[i] = *(const short8*)&As[((mt * 2 + kst) * 64 + lane) * 8];
                int ot = ohalf * 4 + i;
                wf[i] = *(const short8*)&Ws[((ot * 2 + kst) * 64 + lane) * 8];
            }
#pragma unroll
            for (int i = 0; i < 4; ++i)
#pragma unroll
                for (int j = 0; j < 4; ++j)
                    acc[i][j] = __builtin_amdgcn_mfma_f32_16x16x32_bf16(
                        af[i], wf[j], acc[i][j], 0, 0, 0);
        }
        __syncthreads();
    }

    // epilogue: C/D layout col=lane&15, row=(lane>>4)*4+reg
#pragma unroll
    for (int i = 0; i < 4; ++i) {
        int r0 = gm0 + (mhalf * 4 + i) * 16 + (lane >> 4) * 4;
#pragma unroll
        for (int j = 0; j < 4; ++j) {
            int oc = o0 + (ohalf * 4 + j) * 16 + (lane & 15);
            float b = bias[oc];
#pragma unroll
            for (int r = 0; r < 4; ++r) {
                int row = r0 + r;
                if (row < M) {
                    float v = acc[i][j][r] + b;
                    if (act) v = 0.5f * v * (1.f + erff(v * 0.70710678118654752f));
                    if (outf) outf[(size_t)row * ostride + oc] = v;
                    if (outb) outb[(size_t)row * ostride + oc] = f2bf(v);
                }
            }
        }
    }
}

// ---------------- edge pass A: alpha + segment-max (encoded-uint atomicMax) --
__device__ __forceinline__ unsigned int enc_f(float f) {
    unsigned int u = __float_as_uint(f);
    return (u & 0x80000000u) ? ~u : (u | 0x80000000u);
}
__device__ __forceinline__ float dec_f(unsigned int u) {
    return __uint_as_float((u & 0x80000000u) ? (u & 0x7FFFFFFFu) : ~u);
}

__global__ __launch_bounds__(256)
void edge_scores_kernel(const float* __restrict__ qkv,
                        const int* __restrict__ src, const int* __restrict__ dst,
                        float* __restrict__ alpha, unsigned int* __restrict__ m,
                        int E)
{
    int idx = blockIdx.x * 256 + threadIdx.x;
    if (idx >= E * N_HEADS) return;
    int e = idx >> 3, hd = idx & 7;
    int s = src[e], d = dst[e];
    const float4* qp = (const float4*)&qkv[(size_t)d * QKV_STRIDE + hd * HEAD_DIM];
    const float4* kp = (const float4*)&qkv[(size_t)s * QKV_STRIDE + 128 + hd * HEAD_DIM];
    float dotv = 0.f;
#pragma unroll
    for (int i = 0; i < 4; ++i) {
        float4 qv = qp[i], kv = kp[i];
        dotv += qv.x * kv.x + qv.y * kv.y + qv.z * kv.z + qv.w * kv.w;
    }
    float a = dotv * 0.25f;   // 1/sqrt(16)
    alpha[idx] = a;
    atomicMax(&m[d * N_HEADS + hd], enc_f(a));
}

// ---------------- edge pass B: ea = exp(a-m); agg += ea*v; denom += ea -------
__global__ __launch_bounds__(256)
void edge_agg_kernel(const float* __restrict__ qkv, const int* __restrict__ src,
                     const int* __restrict__ dst, const float* __restrict__ alpha,
                     const unsigned int* __restrict__ m, float* __restrict__ agg,
                     float* __restrict__ denom, int E)
{
    int idx = blockIdx.x * 256 + threadIdx.x;
    if (idx >= E * HID) return;   // 102.4M < 2^31
    int e = idx >> 7, c = idx & 127, hd = c >> 4;
    int s = src[e], d = dst[e];
    float a  = alpha[e * N_HEADS + hd];
    float mv = dec_f(m[d * N_HEADS + hd]);
    float ea = __expf(a - mv);
    if ((c & 15) == 0) atomicAdd(&denom[d * N_HEADS + hd], ea);
    atomicAdd(&agg[(size_t)d * HID + c], ea * qkv[(size_t)s * QKV_STRIDE + 256 + c]);
}

// ---------------- normalize agg by denom -> bf16 -----------------------------
__global__ __launch_bounds__(256)
void norm_agg_kernel(const float* __restrict__ agg, const float* __restrict__ denom,
                     ushort_t* __restrict__ aggb, int N)
{
    int idx = blockIdx.x * 256 + threadIdx.x;
    if (idx >= N * HID) return;
    int n = idx >> 7, hd = (idx & 127) >> 4;
    aggb[idx] = f2bf(agg[idx] / (denom[n * N_HEADS + hd] + 1e-16f));
}

// ---------------- fused add + layernorm: out = LN(a+b)*g+be (+opt bf16) ------
__global__ __launch_bounds__(256)
void add_ln_kernel(const float* __restrict__ a, const float* __restrict__ b,
                   const float* __restrict__ g, const float* __restrict__ be,
                   float* __restrict__ out, ushort_t* __restrict__ outb, int N)
{
    int wave = threadIdx.x >> 6;
    int lane = threadIdx.x & 63;
    int n = blockIdx.x * 4 + wave;
    if (n >= N) return;
    int c = lane * 2;
    float2 av = *(const float2*)&a[(size_t)n * HID + c];
    float2 bv = *(const float2*)&b[(size_t)n * HID + c];
    float v0 = av.x + bv.x, v1 = av.y + bv.y;
    float s = v0 + v1;
#pragma unroll
    for (int off = 32; off; off >>= 1) s += __shfl_down(s, off);
    s = __shfl(s, 0);
    float mu = s * (1.f / 128.f);
    float d0 = v0 - mu, d1 = v1 - mu;
    float vs = d0 * d0 + d1 * d1;
#pragma unroll
    for (int off = 32; off; off >>= 1) vs += __shfl_down(vs, off);
    vs = __shfl(vs, 0);
    float rstd = rsqrtf(vs * (1.f / 128.f) + 1e-5f);
    float o0 = d0 * rstd * g[c] + be[c];
    float o1 = d1 * rstd * g[c + 1] + be[c + 1];
    out[(size_t)n * HID + c]     = o0;
    out[(size_t)n * HID + c + 1] = o1;
    if (outb) {
        outb[(size_t)n * HID + c]     = f2bf(o0);
        outb[(size_t)n * HID + c + 1] = f2bf(o1);
    }
}

// ============================================================================
extern "C" void kernel_launch(void* const* d_in, const int* in_sizes, int n_in,
                              void* d_out, int out_size, void* d_ws, size_t ws_size,
                              hipStream_t stream)
{
    const float* x  = (const float*)d_in[0];
    const int*   ei = (const int*)d_in[1];
    const float* Wq = (const float*)d_in[2];
    const float* bq = (const float*)d_in[3];
    const float* Wk = (const float*)d_in[4];
    const float* bk = (const float*)d_in[5];
    const float* Wv = (const float*)d_in[6];
    const float* bv = (const float*)d_in[7];
    const float* Wo = (const float*)d_in[8];
    const float* bo = (const float*)d_in[9];
    const float* W1 = (const float*)d_in[10];
    const float* b1 = (const float*)d_in[11];
    const float* W2 = (const float*)d_in[12];
    const float* b2 = (const float*)d_in[13];
    const float* g1 = (const float*)d_in[14];
    const float* be1= (const float*)d_in[15];
    const float* g2 = (const float*)d_in[16];
    const float* be2= (const float*)d_in[17];
    float* out = (float*)d_out;

    const int N = in_sizes[0] / HID;      // 50000
    const int E = in_sizes[1] / 2;        // 800000
    const int* srcp = ei;
    const int* dstp = ei + E;

    const size_t NH  = (size_t)N * HID;   // 6.4M
    const size_t HN2 = NH / 2;
    const size_t N8  = (size_t)N * N_HEADS;
    float* wsf = (float*)d_ws;

    // ---- workspace layout (f32 units, overlays annotated) ----
    ushort_t* xb   = (ushort_t*)wsf;                 // [0, 0.5NH)   dies after QKV
    float*    qkv  = wsf + HN2;                      // [0.5, 3.5)   dies after edge_agg
    float*    alpha= wsf + HN2 + 3 * NH;             // [3.5, 4.5)   dies after edge_agg
    float*    agg  = wsf + HN2 + 4 * NH;             // [4.5, 5.5)   dies after norm_agg
    float*    mden = wsf + HN2 + 5 * NH;             // [5.5, +2N8)  m then denom
    ushort_t* wts  = (ushort_t*)(wsf + HN2 + 5 * NH + 2 * N8);   // 196608 ushort
    float*    bqkv = wsf + HN2 + 5 * NH + 2 * N8 + 98304;        // 384 f32
    float*    h    = wsf;                            // [0, 1)     overlays xb+qkv head
    ushort_t* aggb = (ushort_t*)(wsf + NH);          // [1.0, 1.5) overlays dead qkv
    ushort_t* hb   = (ushort_t*)(wsf + NH + HN2);    // [1.5, 2.0) overlays dead qkv
    ushort_t* ffb  = (ushort_t*)(wsf + 2 * NH);      // [2.0, 4.0) overlays dead qkv/alpha
    float*    ff2  = wsf + 4 * NH;                   // [4.0, 5.0) overlays dead alpha/att
    float*    att  = agg;                            // reuse agg slot (fp32 agg dead)

    // ---- bf16 conversions ----
    cvt_bf16_kernel<<<(int)((HN2 + 255) / 256), 256, 0, stream>>>(x, xb, (int)HN2);
    cvt_bf16_kernel<<<32, 256, 0, stream>>>(Wq, wts,          8192);
    cvt_bf16_kernel<<<32, 256, 0, stream>>>(Wk, wts + 16384,  8192);
    cvt_bf16_kernel<<<32, 256, 0, stream>>>(Wv, wts + 32768,  8192);
    cvt_bf16_kernel<<<32, 256, 0, stream>>>(Wo, wts + 49152,  8192);
    cvt_bf16_kernel<<<128, 256, 0, stream>>>(W1, wts + 65536, 32768);
    cvt_bf16_kernel<<<128, 256, 0, stream>>>(W2, wts + 131072,32768);
    hipMemcpyAsync(bqkv,       bq, 128 * sizeof(float), hipMemcpyDeviceToDevice, stream);
    hipMemcpyAsync(bqkv + 128, bk, 128 * sizeof(float), hipMemcpyDeviceToDevice, stream);
    hipMemcpyAsync(bqkv + 256, bv, 128 * sizeof(float), hipMemcpyDeviceToDevice, stream);

    const int gx = (N + 127) / 128;   // 391

    // ---- QKV (fused, O=384) ----
    gemm_bf16<<<dim3(gx, 3), 256, 0, stream>>>(xb, HID, N, wts, HID, bqkv,
                                               qkv, nullptr, QKV_STRIDE, 0);

    // zero agg + m + denom (enc(-inf) > 0, so 0 is valid atomicMax identity)
    hipMemsetAsync(agg, 0, (NH + 2 * N8) * sizeof(float), stream);

    edge_scores_kernel<<<(E * N_HEADS + 255) / 256, 256, 0, stream>>>(
        qkv, srcp, dstp, alpha, (unsigned int*)mden, E);

    {
        long long total = (long long)E * HID;
        edge_agg_kernel<<<(int)((total + 255) / 256), 256, 0, stream>>>(
            qkv, srcp, dstp, alpha, (const unsigned int*)mden, agg, mden + N8, E);
    }
    norm_agg_kernel<<<(int)((NH + 255) / 256), 256, 0, stream>>>(agg, mden + N8, aggb, N);

    // ---- Wo + residual/LN1 (h fp32 + hb bf16) ----
    gemm_bf16<<<dim3(gx, 1), 256, 0, stream>>>(aggb, HID, N, wts + 49152, HID, bo,
                                               att, nullptr, HID, 0);
    add_ln_kernel<<<(N + 3) / 4, 256, 0, stream>>>(x, att, g1, be1, h, hb, N);

    // ---- FFN ----
    gemm_bf16<<<dim3(gx, 4), 256, 0, stream>>>(hb, HID, N, wts + 65536, HID, b1,
                                               nullptr, ffb, 512, 1);
    gemm_bf16<<<dim3(gx, 1), 256, 0, stream>>>(ffb, 512, N, wts + 131072, 512, b2,
                                               ff2, nullptr, HID, 0);
    add_ln_kernel<<<(N + 3) / 4, 256, 0, stream>>>(h, ff2, g2, be2, out, nullptr, N);
}

// Round 3
// 492.928 us; speedup vs baseline: 2.5499x; 1.7422x over previous
//
#include <hip/hip_runtime.h>
#include <math.h>

#define N_HEADS 8
#define HEAD_DIM 16
#define HID 128
#define QKV_STRIDE 384

typedef unsigned short ushort_t;
typedef __attribute__((ext_vector_type(8))) short short8;
typedef __attribute__((ext_vector_type(4))) float floatx4;

__device__ __forceinline__ ushort_t f2bf(float f) {
    unsigned u = __float_as_uint(f);
    unsigned r = (u + 0x7FFFu + ((u >> 16) & 1u)) >> 16;
    return (ushort_t)r;
}
__device__ __forceinline__ float bf2f(ushort_t u) {
    return __uint_as_float(((unsigned)u) << 16);
}

__device__ __forceinline__ void gld_lds16(const void* g, void* l) {
    __builtin_amdgcn_global_load_lds(
        (const __attribute__((address_space(1))) void*)g,
        (__attribute__((address_space(3))) void*)l, 16, 0, 0);
}

// ---------------- f32 -> bf16 conversion (2 elems/thread) --------------------
__global__ __launch_bounds__(256)
void cvt_bf16_kernel(const float* __restrict__ in, ushort_t* __restrict__ out, int n2)
{
    int i = blockIdx.x * 256 + threadIdx.x;
    if (i >= n2) return;
    float2 v = *(const float2*)&in[i * 2];
    out[i * 2]     = f2bf(v.x);
    out[i * 2 + 1] = f2bf(v.y);
}

// ---------------- bf16 MFMA GEMM: out[M,O] = act(A[M,K] @ W[O,K]^T + b) ------
__global__ __launch_bounds__(256)
void gemm_bf16(const ushort_t* __restrict__ A, int lda, int M,
               const ushort_t* __restrict__ W, int K,
               const float* __restrict__ bias,
               float* __restrict__ outf, ushort_t* __restrict__ outb,
               int ostride, int act)
{
    __shared__ __align__(16) ushort_t As[128 * 64];
    __shared__ __align__(16) ushort_t Ws[128 * 64];
    const int tid  = threadIdx.x;
    const int wave = tid >> 6, lane = tid & 63;
    const int gm0 = blockIdx.x * 128;
    const int o0  = blockIdx.y * 128;
    const int mhalf = wave >> 1, ohalf = wave & 1;

    floatx4 acc[4][4];
#pragma unroll
    for (int i = 0; i < 4; ++i)
#pragma unroll
        for (int j = 0; j < 4; ++j) acc[i][j] = (floatx4)(0.f);

    for (int kc = 0; kc < K; kc += 64) {
#pragma unroll
        for (int it = 0; it < 4; ++it) {
            int s   = it * 256 + tid;
            int ln  = s & 63;
            int grp = s >> 6;
            int tile = grp >> 1, kst = grp & 1;
            int row = tile * 16 + (ln & 15);
            int kk  = kst * 32 + (ln >> 4) * 8;
            int ldsbase = (it * 256 + wave * 64) * 8;
            int ar = gm0 + row; if (ar >= M) ar = M - 1;
            gld_lds16(&A[(size_t)ar * lda + kc + kk], &As[ldsbase]);
            gld_lds16(&W[(size_t)(o0 + row) * K + kc + kk], &Ws[ldsbase]);
        }
        __syncthreads();
#pragma unroll
        for (int kst = 0; kst < 2; ++kst) {
            short8 af[4], wf[4];
#pragma unroll
            for (int i = 0; i < 4; ++i) {
                int mt = mhalf * 4 + i;
                af[i] = *(const short8*)&As[((mt * 2 + kst) * 64 + lane) * 8];
                int ot = ohalf * 4 + i;
                wf[i] = *(const short8*)&Ws[((ot * 2 + kst) * 64 + lane) * 8];
            }
#pragma unroll
            for (int i = 0; i < 4; ++i)
#pragma unroll
                for (int j = 0; j < 4; ++j)
                    acc[i][j] = __builtin_amdgcn_mfma_f32_16x16x32_bf16(
                        af[i], wf[j], acc[i][j], 0, 0, 0);
        }
        __syncthreads();
    }

#pragma unroll
    for (int i = 0; i < 4; ++i) {
        int r0 = gm0 + (mhalf * 4 + i) * 16 + (lane >> 4) * 4;
#pragma unroll
        for (int j = 0; j < 4; ++j) {
            int oc = o0 + (ohalf * 4 + j) * 16 + (lane & 15);
            float b = bias[oc];
#pragma unroll
            for (int r = 0; r < 4; ++r) {
                int row = r0 + r;
                if (row < M) {
                    float v = acc[i][j][r] + b;
                    if (act) v = 0.5f * v * (1.f + erff(v * 0.70710678118654752f));
                    if (outf) outf[(size_t)row * ostride + oc] = v;
                    if (outb) outb[(size_t)row * ostride + oc] = f2bf(v);
                }
            }
        }
    }
}

// ---------------- counting sort: count, scan (3 kernels), scatter ------------
__global__ __launch_bounds__(256)
void count_kernel(const int* __restrict__ dst, int* __restrict__ cnt, int E)
{
    int e = blockIdx.x * 256 + threadIdx.x;
    if (e < E) atomicAdd(&cnt[dst[e]], 1);
}

__global__ __launch_bounds__(256)
void scan1_kernel(const int* __restrict__ cnt, int* __restrict__ parts, int N)
{
    __shared__ int sd[256];
    int t = threadIdx.x;
    int base = blockIdx.x * 1024 + t * 4;
    int s = 0;
#pragma unroll
    for (int j = 0; j < 4; ++j) if (base + j < N) s += cnt[base + j];
    sd[t] = s; __syncthreads();
    for (int off = 128; off; off >>= 1) {
        if (t < off) sd[t] += sd[t + off];
        __syncthreads();
    }
    if (t == 0) parts[blockIdx.x] = sd[0];
}

__global__ __launch_bounds__(256)
void scan2_kernel(const int* __restrict__ parts, int* __restrict__ poff, int nb)
{
    __shared__ int sd[256];
    int t = threadIdx.x;
    int v = (t < nb) ? parts[t] : 0;
    sd[t] = v; __syncthreads();
    for (int off = 1; off < 256; off <<= 1) {
        int u = (t >= off) ? sd[t - off] : 0;
        __syncthreads();
        sd[t] += u;
        __syncthreads();
    }
    if (t < nb) poff[t] = sd[t] - v;   // exclusive
}

__global__ __launch_bounds__(256)
void scan3_kernel(const int* __restrict__ cnt, const int* __restrict__ poff,
                  int* __restrict__ rp, int N)
{
    __shared__ int sd[256];
    int t = threadIdx.x;
    int base = blockIdx.x * 1024 + t * 4;
    int v0 = (base + 0 < N) ? cnt[base + 0] : 0;
    int v1 = (base + 1 < N) ? cnt[base + 1] : 0;
    int v2 = (base + 2 < N) ? cnt[base + 2] : 0;
    int v3 = (base + 3 < N) ? cnt[base + 3] : 0;
    int s = v0 + v1 + v2 + v3;
    sd[t] = s; __syncthreads();
    for (int off = 1; off < 256; off <<= 1) {
        int u = (t >= off) ? sd[t - off] : 0;
        __syncthreads();
        sd[t] += u;
        __syncthreads();
    }
    int o = poff[blockIdx.x] + sd[t] - s;
    if (base + 0 < N) rp[base + 0] = o;
    if (base + 1 < N) rp[base + 1] = o + v0;
    if (base + 2 < N) rp[base + 2] = o + v0 + v1;
    if (base + 3 < N) rp[base + 3] = o + v0 + v1 + v2;
}

// after this pass, rp[d] = end of segment d (start = d ? rp[d-1] : 0)
__global__ __launch_bounds__(256)
void scatter_kernel(const int* __restrict__ src, const int* __restrict__ dst,
                    int* __restrict__ rp, int* __restrict__ ssrc, int E)
{
    int e = blockIdx.x * 256 + threadIdx.x;
    if (e >= E) return;
    int pos = atomicAdd(&rp[dst[e]], 1);
    ssrc[pos] = src[e];
}

// ---------------- fused attention: one wave per dst node ---------------------
// lane owns channels {2*lane, 2*lane+1}; head = lane>>3 (8 lanes x 16 ch/head).
// Online softmax per head, no global atomics.
__global__ __launch_bounds__(256)
void attn_fused_kernel(const ushort_t* __restrict__ qkvb, const int* __restrict__ rp,
                       const int* __restrict__ ssrc, ushort_t* __restrict__ aggb, int N)
{
    int wave = threadIdx.x >> 6, lane = threadIdx.x & 63;
    int n = blockIdx.x * 4 + wave;
    if (n >= N) return;
    int c = lane * 2;
    ushort2 qu = *(const ushort2*)&qkvb[(size_t)n * QKV_STRIDE + c];
    float qx = bf2f(qu.x) * 0.25f, qy = bf2f(qu.y) * 0.25f;   // scale = 1/sqrt(16)
    int r0 = n ? rp[n - 1] : 0;
    int r1 = rp[n];
    float m = -INFINITY, l = 0.f, a0 = 0.f, a1 = 0.f;
    for (int r = r0; r < r1; ++r) {
        int s = ssrc[r];
        ushort2 ku = *(const ushort2*)&qkvb[(size_t)s * QKV_STRIDE + HID + c];
        float p = qx * bf2f(ku.x) + qy * bf2f(ku.y);
        p += __shfl_xor(p, 1);
        p += __shfl_xor(p, 2);
        p += __shfl_xor(p, 4);            // per-head dot (8 lanes/head)
        float mn = fmaxf(m, p);
        float sc = __expf(m - mn);        // m=-inf on first iter -> 0
        float ea = __expf(p - mn);
        ushort2 vu = *(const ushort2*)&qkvb[(size_t)s * QKV_STRIDE + 2 * HID + c];
        l  = l  * sc + ea;
        a0 = a0 * sc + ea * bf2f(vu.x);
        a1 = a1 * sc + ea * bf2f(vu.y);
        m = mn;
    }
    float inv = 1.f / (l + 1e-16f);
    aggb[(size_t)n * HID + c]     = f2bf(a0 * inv);
    aggb[(size_t)n * HID + c + 1] = f2bf(a1 * inv);
}

// ---------------- fused add + layernorm (a = f32 or bf16) --------------------
__global__ __launch_bounds__(256)
void add_ln_kernel(const float* __restrict__ a, const ushort_t* __restrict__ ab,
                   const float* __restrict__ b,
                   const float* __restrict__ g, const float* __restrict__ be,
                   float* __restrict__ out, ushort_t* __restrict__ outb, int N)
{
    int wave = threadIdx.x >> 6;
    int lane = threadIdx.x & 63;
    int n = blockIdx.x * 4 + wave;
    if (n >= N) return;
    int c = lane * 2;
    float2 av;
    if (a) av = *(const float2*)&a[(size_t)n * HID + c];
    else {
        ushort2 t = *(const ushort2*)&ab[(size_t)n * HID + c];
        av = make_float2(bf2f(t.x), bf2f(t.y));
    }
    float2 bv = *(const float2*)&b[(size_t)n * HID + c];
    float v0 = av.x + bv.x, v1 = av.y + bv.y;
    float s = v0 + v1;
#pragma unroll
    for (int off = 32; off; off >>= 1) s += __shfl_down(s, off);
    s = __shfl(s, 0);
    float mu = s * (1.f / 128.f);
    float d0 = v0 - mu, d1 = v1 - mu;
    float vs = d0 * d0 + d1 * d1;
#pragma unroll
    for (int off = 32; off; off >>= 1) vs += __shfl_down(vs, off);
    vs = __shfl(vs, 0);
    float rstd = rsqrtf(vs * (1.f / 128.f) + 1e-5f);
    float o0 = d0 * rstd * g[c] + be[c];
    float o1 = d1 * rstd * g[c + 1] + be[c + 1];
    if (out) {
        out[(size_t)n * HID + c]     = o0;
        out[(size_t)n * HID + c + 1] = o1;
    }
    if (outb) {
        outb[(size_t)n * HID + c]     = f2bf(o0);
        outb[(size_t)n * HID + c + 1] = f2bf(o1);
    }
}

// ============================================================================
extern "C" void kernel_launch(void* const* d_in, const int* in_sizes, int n_in,
                              void* d_out, int out_size, void* d_ws, size_t ws_size,
                              hipStream_t stream)
{
    const float* x  = (const float*)d_in[0];
    const int*   ei = (const int*)d_in[1];
    const float* Wq = (const float*)d_in[2];
    const float* bq = (const float*)d_in[3];
    const float* Wk = (const float*)d_in[4];
    const float* bk = (const float*)d_in[5];
    const float* Wv = (const float*)d_in[6];
    const float* bv = (const float*)d_in[7];
    const float* Wo = (const float*)d_in[8];
    const float* bo = (const float*)d_in[9];
    const float* W1 = (const float*)d_in[10];
    const float* b1 = (const float*)d_in[11];
    const float* W2 = (const float*)d_in[12];
    const float* b2 = (const float*)d_in[13];
    const float* g1 = (const float*)d_in[14];
    const float* be1= (const float*)d_in[15];
    const float* g2 = (const float*)d_in[16];
    const float* be2= (const float*)d_in[17];
    float* out = (float*)d_out;

    const int N = in_sizes[0] / HID;      // 50000
    const int E = in_sizes[1] / 2;        // 800000
    const int* srcp = ei;
    const int* dstp = ei + E;

    const size_t NH = (size_t)N * HID;    // 6.4M
    float* wsf = (float*)d_ws;

    // ---- workspace layout (f32 units; peak 3.5*NH + ~4 MB ≈ 94 MB) ----
    ushort_t* xb   = (ushort_t*)wsf;                  // [0, 0.5NH)  dies after QKV
    ushort_t* qkvb = (ushort_t*)(wsf + NH / 2);       // [0.5, 2.0)  dies after attn
    ushort_t* aggb = (ushort_t*)(wsf + 2 * NH);       // [2.0, 2.5)  dies after Wo
    float*    att  = wsf + 2 * NH + NH / 2;           // [2.5, 3.5)  dies after ln1
    ushort_t* hb   = (ushort_t*)wsf;                  // [0, 0.5)    overlays dead xb
    ushort_t* ffb  = (ushort_t*)(wsf + NH / 2);       // [0.5, 2.5)  overlays dead qkvb+aggb
    float*    ff2  = att;                             // [2.5, 3.5)  overlays dead att

    ushort_t* wts  = (ushort_t*)(wsf + 3 * NH + NH / 2);  // 196608 ushort (16B-aligned)
    float*    bqkv = (float*)(wts + 196608);              // 384 f32
    int*      rp   = (int*)(bqkv + 384);                  // N+1
    int*      cnt  = rp + (N + 1);                        // N
    int*      poff = cnt + N;                             // 256
    int*      parts= poff + 256;                          // 256
    int*      ssrc = parts + 256;                         // E

    // ---- bf16 conversions ----
    cvt_bf16_kernel<<<(int)((NH / 2 + 255) / 256), 256, 0, stream>>>(x, xb, (int)(NH / 2));
    cvt_bf16_kernel<<<32, 256, 0, stream>>>(Wq, wts,          8192);
    cvt_bf16_kernel<<<32, 256, 0, stream>>>(Wk, wts + 16384,  8192);
    cvt_bf16_kernel<<<32, 256, 0, stream>>>(Wv, wts + 32768,  8192);
    cvt_bf16_kernel<<<32, 256, 0, stream>>>(Wo, wts + 49152,  8192);
    cvt_bf16_kernel<<<128, 256, 0, stream>>>(W1, wts + 65536, 32768);
    cvt_bf16_kernel<<<128, 256, 0, stream>>>(W2, wts + 131072,32768);
    hipMemcpyAsync(bqkv,       bq, 128 * sizeof(float), hipMemcpyDeviceToDevice, stream);
    hipMemcpyAsync(bqkv + 128, bk, 128 * sizeof(float), hipMemcpyDeviceToDevice, stream);
    hipMemcpyAsync(bqkv + 256, bv, 128 * sizeof(float), hipMemcpyDeviceToDevice, stream);

    // ---- counting sort of edges by dst ----
    hipMemsetAsync(cnt, 0, N * sizeof(int), stream);
    count_kernel<<<(E + 255) / 256, 256, 0, stream>>>(dstp, cnt, E);
    const int nb = (N + 1023) / 1024;   // 49
    scan1_kernel<<<nb, 256, 0, stream>>>(cnt, parts, N);
    scan2_kernel<<<1, 256, 0, stream>>>(parts, poff, nb);
    scan3_kernel<<<nb, 256, 0, stream>>>(cnt, poff, rp, N);
    scatter_kernel<<<(E + 255) / 256, 256, 0, stream>>>(srcp, dstp, rp, ssrc, E);

    const int gx = (N + 127) / 128;   // 391

    // ---- QKV (fused, O=384, bf16 out) ----
    gemm_bf16<<<dim3(gx, 3), 256, 0, stream>>>(xb, HID, N, wts, HID, bqkv,
                                               nullptr, qkvb, QKV_STRIDE, 0);

    // ---- fused attention (no atomics) ----
    attn_fused_kernel<<<(N + 3) / 4, 256, 0, stream>>>(qkvb, rp, ssrc, aggb, N);

    // ---- Wo + residual/LN1 (bf16 h) ----
    gemm_bf16<<<dim3(gx, 1), 256, 0, stream>>>(aggb, HID, N, wts + 49152, HID, bo,
                                               att, nullptr, HID, 0);
    add_ln_kernel<<<(N + 3) / 4, 256, 0, stream>>>(x, nullptr, att, g1, be1,
                                                   nullptr, hb, N);

    // ---- FFN ----
    gemm_bf16<<<dim3(gx, 4), 256, 0, stream>>>(hb, HID, N, wts + 65536, HID, b1,
                                               nullptr, ffb, 512, 1);
    gemm_bf16<<<dim3(gx, 1), 256, 0, stream>>>(ffb, 512, N, wts + 131072, 512, b2,
                                               ff2, nullptr, HID, 0);
    add_ln_kernel<<<(N + 3) / 4, 256, 0, stream>>>(nullptr, hb, ff2, g2, be2,
                                                   out, nullptr, N);
}